// Round 1
// 1290.728 us; speedup vs baseline: 1.1066x; 1.1066x over previous
//
#include <hip/hip_runtime.h>
#include <math.h>

#define SS 128
#define BB 64
#define VV 32000
#define EE 32
#define HH 16
#define NROW (SS*BB)   // 8192
#define RT 16          // rows per block in the fused lse+out kernel

typedef float f32x4 __attribute__((ext_vector_type(4)));

// ---------------------------------------------------------------------------
// Kernel 1: Elman recurrence. One 64-lane wave per batch element.
// Lane j (j = lane & 15) owns h_j; weight columns live in registers;
// cross-lane data (x row, previous h) moves via __shfl (wave = 64 lanes).
// NEW: all 128 tokens for this b are pre-loaded into two lane-indexed
// registers (no per-step s_load), and the embedding row is prefetched at
// distance 2 so the L2/HBM latency hides under two steps of compute.
// Arithmetic order is IDENTICAL to the previous version.
// ---------------------------------------------------------------------------
__global__ __launch_bounds__(64) void rnn_recurrence(
        const int*   __restrict__ idx,     // [S,B]
        const float* __restrict__ lookup,  // [V,E]
        const float* __restrict__ Wx,      // [E,H]
        const float* __restrict__ Wh,      // [H,H]
        const float* __restrict__ h0,      // [B,H]
        float*       __restrict__ Hmat) {  // [S*B,H]
    const int b    = blockIdx.x;
    const int lane = threadIdx.x;          // 0..63
    const int j    = lane & (HH - 1);      // lanes >=16 duplicate lanes 0..15
    const int exl  = lane & (EE - 1);      // lanes 0..31 carry x

    float wxj[EE];
    #pragma unroll
    for (int e = 0; e < EE; ++e) wxj[e] = Wx[e * HH + j];
    float whj[HH];
    #pragma unroll
    for (int k = 0; k < HH; ++k) whj[k] = Wh[k * HH + j];

    // Token prefetch: lane t holds token for step t (and t+64).
    const int tokA = idx[lane * BB + b];          // t = 0..63
    const int tokB = idx[(lane + 64) * BB + b];   // t = 64..127

    float hj = h0[b * HH + j];

    // Embedding prefetch pipeline, distance 2.
    int tk0 = __shfl(tokA, 0);
    float xv_c = lookup[tk0 * EE + exl];          // x for t
    int tk1 = __shfl(tokA, 1);
    float xv_n = lookup[tk1 * EE + exl];          // x for t+1

    for (int t = 0; t < SS; ++t) {
        float xv_f = 0.f;                          // x for t+2
        if (t + 2 < SS) {
            const int tf  = t + 2;
            const int tok = __shfl((tf & 64) ? tokB : tokA, tf & 63);
            xv_f = lookup[tok * EE + exl];
        }

        float a0 = 0.f, a1 = 0.f, a2 = 0.f, a3 = 0.f;    // 4 chains for ILP
        #pragma unroll
        for (int e = 0; e < EE; e += 4) {
            a0 += __shfl(xv_c, e)     * wxj[e];
            a1 += __shfl(xv_c, e + 1) * wxj[e + 1];
            a2 += __shfl(xv_c, e + 2) * wxj[e + 2];
            a3 += __shfl(xv_c, e + 3) * wxj[e + 3];
        }
        #pragma unroll
        for (int k = 0; k < HH; k += 4) {
            a0 += __shfl(hj, k)     * whj[k];
            a1 += __shfl(hj, k + 1) * whj[k + 1];
            a2 += __shfl(hj, k + 2) * whj[k + 2];
            a3 += __shfl(hj, k + 3) * whj[k + 3];
        }
        hj = tanhf((a0 + a1) + (a2 + a3));
        if (lane < HH) Hmat[(t * BB + b) * HH + j] = hj;

        xv_c = xv_n; xv_n = xv_f;
    }
}

// ---------------------------------------------------------------------------
// Kernel 2 (fused): per-row log-sum-exp (pass 1, identical summation order to
// the old rnn_lse) then recompute-and-write log-probs (pass 2, identical to
// the old rnn_out) with NONTEMPORAL stores so the 1 GB write stream does not
// evict the 2 MB Wo panel from the XCD L2s.
// Logits are bounded (|l| < ~3), so no max-shift is needed: exp can't overflow.
// ---------------------------------------------------------------------------
__global__ __launch_bounds__(256) void rnn_lse_out(
        const float* __restrict__ Hmat,   // [NROW,H]
        const float* __restrict__ Wo,     // [H,V]
        float*       __restrict__ out) {  // [NROW, V]
    const int row0 = blockIdx.x * RT;
    const int tid  = threadIdx.x;

    // ---------------- pass 1: sum of exp(logits) per row ----------------
    float s[RT];
    #pragma unroll
    for (int r = 0; r < RT; ++r) s[r] = 0.f;

    for (int jc = tid; jc < VV / 4; jc += 256) {
        float4 wc[HH];
        #pragma unroll
        for (int k = 0; k < HH; ++k)
            wc[k] = ((const float4*)(Wo + k * VV))[jc];
        #pragma unroll
        for (int r = 0; r < RT; ++r) {
            const float* h = Hmat + (row0 + r) * HH;  // uniform address -> s_load
            float l0 = 0.f, l1 = 0.f, l2 = 0.f, l3 = 0.f;
            #pragma unroll
            for (int k = 0; k < HH; ++k) {
                const float hk = h[k];
                l0 += hk * wc[k].x; l1 += hk * wc[k].y;
                l2 += hk * wc[k].z; l3 += hk * wc[k].w;
            }
            s[r] += (__expf(l0) + __expf(l1)) + (__expf(l2) + __expf(l3));
        }
    }

    // block reduction: wave shuffle-reduce, then cross-wave via LDS
    #pragma unroll
    for (int r = 0; r < RT; ++r) {
        float v = s[r];
        #pragma unroll
        for (int off = 32; off >= 1; off >>= 1)
            v += __shfl_down(v, off);
        s[r] = v;
    }
    __shared__ float red[4][RT];
    __shared__ float lse_sh[RT];
    const int wave = tid >> 6;
    if ((tid & 63) == 0) {
        #pragma unroll
        for (int r = 0; r < RT; ++r) red[wave][r] = s[r];
    }
    __syncthreads();
    if (tid < RT) {
        const float tot = (red[0][tid] + red[1][tid]) + (red[2][tid] + red[3][tid]);
        lse_sh[tid] = __logf(tot);
    }
    __syncthreads();

    float mr[RT];
    #pragma unroll
    for (int r = 0; r < RT; ++r) mr[r] = lse_sh[r];

    // ---------------- pass 2: recompute logits, subtract lse, stream out ----
    for (int jc = tid; jc < VV / 4; jc += 256) {
        float4 wc[HH];
        #pragma unroll
        for (int k = 0; k < HH; ++k)
            wc[k] = ((const float4*)(Wo + k * VV))[jc];
        #pragma unroll
        for (int r = 0; r < RT; ++r) {
            const int row = row0 + r;
            const float* h = Hmat + row * HH;          // uniform -> s_load
            float l0 = 0.f, l1 = 0.f, l2 = 0.f, l3 = 0.f;
            #pragma unroll
            for (int k = 0; k < HH; ++k) {
                const float hk = h[k];
                l0 += hk * wc[k].x; l1 += hk * wc[k].y;
                l2 += hk * wc[k].z; l3 += hk * wc[k].w;
            }
            const float m = mr[r];
            f32x4 o;
            o.x = l0 - m; o.y = l1 - m; o.z = l2 - m; o.w = l3 - m;
            __builtin_nontemporal_store(o, (f32x4*)(out + (size_t)row * VV) + jc);
        }
    }
}

// ---------------------------------------------------------------------------
extern "C" void kernel_launch(void* const* d_in, const int* in_sizes, int n_in,
                              void* d_out, int out_size, void* d_ws, size_t ws_size,
                              hipStream_t stream) {
    const int*   idx    = (const int*)  d_in[0];  // [S,B] int32
    const float* lookup = (const float*)d_in[1];  // [V,E]
    const float* Wx     = (const float*)d_in[2];  // [E,H]
    const float* Wh     = (const float*)d_in[3];  // [H,H]
    const float* Wo     = (const float*)d_in[4];  // [H,V]
    const float* h0     = (const float*)d_in[5];  // [B,H]
    float* out = (float*)d_out;

    float* Hmat = (float*)d_ws;            // NROW*H floats = 512 KB

    rnn_recurrence<<<BB, 64, 0, stream>>>(idx, lookup, Wx, Wh, h0, Hmat);
    rnn_lse_out<<<NROW / RT, 256, 0, stream>>>(Hmat, Wo, out);
}